// Round 16
// baseline (91.014 us; speedup 1.0000x reference)
//
#include <hip/hip_runtime.h>
#include <hip/hip_bf16.h>

// Problem: SelfAttention1d  B=4, L=2048, C=256, H=8, D=32.
// dtypes: inputs fp32, output fp32.
// ws layout (bf16): Q (B,H,L,D) | K (B,H,L,D) | Vt (B,H,D,L) | O (B,L,C) = 16MB.
// Round 16: fix r15's V-scratch stride collision (Vx[d][m] with stride 40
// aliased rows for m>=40; now flat scratch, stride 40 for Q/K rows,
// stride 72 for V d-rows). Everything else = r15.

typedef __bf16 bf16x4 __attribute__((ext_vector_type(4)));
typedef __bf16 bf16x8 __attribute__((ext_vector_type(8)));
typedef float  f32x4  __attribute__((ext_vector_type(4)));

#define MFMA16(a, b, c) __builtin_amdgcn_mfma_f32_16x16x32_bf16((a), (b), (c), 0, 0, 0)

static constexpr int Bsz = 4, L = 2048, C = 256, H = 8, D = 32;
static constexpr float SCALE = 0.17677669529663687f;   // 32^-0.5
static constexpr float LOG2E = 1.44269504088896f;
static constexpr float QSCALE = SCALE * LOG2E;         // exp2(S) = softmax exp

__device__ inline float fast_exp2(float x) {
#if __has_builtin(__builtin_amdgcn_exp2f)
    return __builtin_amdgcn_exp2f(x);
#else
    float r; asm("v_exp_f32 %0, %1" : "=v"(r) : "v"(x)); return r;
#endif
}

__device__ inline bf16x8 load_cvt8(const float* __restrict__ p) {
    f32x4 a = *(const f32x4*)(p);
    f32x4 b = *(const f32x4*)(p + 4);
    bf16x8 r;
    r[0] = (__bf16)a[0]; r[1] = (__bf16)a[1]; r[2] = (__bf16)a[2]; r[3] = (__bf16)a[3];
    r[4] = (__bf16)b[0]; r[5] = (__bf16)b[1]; r[6] = (__bf16)b[2]; r[7] = (__bf16)b[3];
    return r;
}

// ---------------------------------------------------------------------------
// Kernel 1: QKV GEMM.  X(8192,256) @ Wqkv(768,256)^T + b -> split into Q,K,Vt.
// Wave tile 64x32 = exactly one (head, q/k/v) chunk. Epilogue: stage in
// per-wave LDS scratch (stride 40 Q/K rows [m][n]; stride 72 V rows [d][m]),
// flat readback -> every store instr writes contiguous full cache lines.
// ---------------------------------------------------------------------------
__global__ __launch_bounds__(256) void qkv_gemm(
    const float* __restrict__ X, const float* __restrict__ W,
    const float* __restrict__ Bq,
    __bf16* __restrict__ Qw, __bf16* __restrict__ Kw, __bf16* __restrict__ Vt)
{
    __shared__ __align__(16) __bf16 Vx[4][2560];   // per-wave epilogue scratch

    const int K = 256;
    const int bm = blockIdx.x & 63, bn = blockIdx.x >> 6;
    const int tid = threadIdx.x, wid = tid >> 6, lane = tid & 63;
    const int lr = lane & 15, lh = lane >> 4;
    const int m0 = bm * 128 + (wid >> 1) * 64;
    const int n0 = bn * 64 + (wid & 1) * 32;

    f32x4 acc[4][2] = {};
    const float* Arow = X + (size_t)(m0 + lr) * K + lh * 8;
    const float* Brow = W + (size_t)(n0 + lr) * K + lh * 8;

    #pragma unroll
    for (int k0 = 0; k0 < 256; k0 += 32) {
        bf16x8 a[4], b[2];
        #pragma unroll
        for (int mt = 0; mt < 4; ++mt) a[mt] = load_cvt8(Arow + mt * 16 * K + k0);
        #pragma unroll
        for (int nt = 0; nt < 2; ++nt) b[nt] = load_cvt8(Brow + nt * 16 * K + k0);
        #pragma unroll
        for (int mt = 0; mt < 4; ++mt)
            #pragma unroll
            for (int nt = 0; nt < 2; ++nt)
                acc[mt][nt] = MFMA16(a[mt], b[nt], acc[mt][nt]);
    }

    const int bb  = m0 >> 11;                 // batch (uniform per wave)
    const int li0 = m0 & 2047;                // 64-row base within batch
    const int h = n0 / 96, r = n0 % 96;
    const int which = r >> 5;                 // 0=Q 1=K 2=V (whole 32-col chunk)
    const int bh = bb * H + h;
    __bf16* sw = Vx[wid];

    if (which == 2) {
        // transposed staging: [d][m], stride 72 (32*72 = 2304 <= 2560)
        #pragma unroll
        for (int nt = 0; nt < 2; ++nt) {
            const float bias = Bq[n0 + nt * 16 + lr];
            #pragma unroll
            for (int mt = 0; mt < 4; ++mt)
                #pragma unroll
                for (int i = 0; i < 4; ++i)
                    sw[(nt * 16 + lr) * 72 + mt * 16 + lh * 4 + i] =
                        (__bf16)(acc[mt][nt][i] + bias);
        }
        // flat readback: c -> (d = c>>3, m-col = (c&7)*8); 16B/lane contiguous
        #pragma unroll
        for (int j = 0; j < 4; ++j) {
            const int c = lane + 64 * j;
            const int d = c >> 3, lc = (c & 7) * 8;
            const bf16x8 v = *(const bf16x8*)(&sw[d * 72 + lc]);
            *(bf16x8*)(Vt + ((size_t)bh * D + d) * L + li0 + lc) = v;
        }
    } else {
        const float scl = (which == 0) ? QSCALE : 1.0f;
        // row-major staging: [m][n], stride 40 (64*40 = 2560)
        #pragma unroll
        for (int nt = 0; nt < 2; ++nt) {
            const float bias = Bq[n0 + nt * 16 + lr];
            #pragma unroll
            for (int mt = 0; mt < 4; ++mt)
                #pragma unroll
                for (int i = 0; i < 4; ++i)
                    sw[(mt * 16 + lh * 4 + i) * 40 + nt * 16 + lr] =
                        (__bf16)((acc[mt][nt][i] + bias) * scl);
        }
        // flat readback: c covers elems 8c..8c+8 of the 64x32 region
        // (m = c>>2, d-col = (c&3)*8); stores are contiguous 1KB per instr
        __bf16* dst = (which == 0 ? Qw : Kw) + ((size_t)bh * L + li0) * D;
        #pragma unroll
        for (int j = 0; j < 4; ++j) {
            const int c = lane + 64 * j;
            const bf16x8 v = *(const bf16x8*)(&sw[(c >> 2) * 40 + (c & 3) * 8]);
            *(bf16x8*)(dst + (size_t)c * 8) = v;
        }
    }
}

// ---------------------------------------------------------------------------
// Kernel 2: flash attention. grid 512 = 32 bh x 16 qt, 256 thr (4 waves).
// Wave w: 32 q-rows (2 fragments) at qt*128 + w*32. Per 64-key tile:
// waves 0-1 stage K, waves 2-3 stage V; all consume. Sum-softmax.
// ---------------------------------------------------------------------------
__global__ __launch_bounds__(256, 2) void attn_fwd(
    const __bf16* __restrict__ Qw, const __bf16* __restrict__ Kw,
    const __bf16* __restrict__ Vt, __bf16* __restrict__ O)
{
    __shared__ __align__(16) __bf16 Kt[64][40];
    __shared__ __align__(16) __bf16 Vl[32][72];
    __shared__ __align__(16) __bf16 Plds[4][16][72];

    const int bid = blockIdx.x;
    const int bh = ((bid & 7) << 2) | ((bid >> 3) & 3);
    const int qt = bid >> 5;
    const int tid = threadIdx.x, wid = tid >> 6, lane = tid & 63;
    const int lr = lane & 15, lh = lane >> 4;
    const int q0 = qt * 128 + wid * 32;

    const __bf16* Qb = Qw + (size_t)bh * L * D;
    const __bf16* Kb = Kw + (size_t)bh * L * D;
    const __bf16* Vb = Vt + (size_t)bh * D * L;

    bf16x8 qf[2];
    #pragma unroll
    for (int tq = 0; tq < 2; ++tq)
        qf[tq] = *(const bf16x8*)(Qb + (size_t)(q0 + tq * 16 + lr) * D + lh * 8);

    f32x4 of[2][2] = {};
    float sacc[2][2] = {};
    const f32x4 zero = {0.f, 0.f, 0.f, 0.f};

    const int t128 = ((wid & 1) << 6) | lane;
    const int kr = t128 >> 1, kc = (t128 & 1) * 16;
    const int vr = t128 >> 2, vc = (t128 & 3) * 16;

    for (int kv = 0; kv < L; kv += 64) {
        if (wid < 2) {
            *(bf16x8*)(&Kt[kr][kc])     = *(const bf16x8*)(Kb + (size_t)(kv + kr) * D + kc);
            *(bf16x8*)(&Kt[kr][kc + 8]) = *(const bf16x8*)(Kb + (size_t)(kv + kr) * D + kc + 8);
        } else {
            *(bf16x8*)(&Vl[vr][vc])     = *(const bf16x8*)(Vb + (size_t)vr * L + kv + vc);
            *(bf16x8*)(&Vl[vr][vc + 8]) = *(const bf16x8*)(Vb + (size_t)vr * L + kv + vc + 8);
        }
        __syncthreads();

        bf16x8 kf[4], vf[2][2];
        #pragma unroll
        for (int t = 0; t < 4; ++t)
            kf[t] = *(const bf16x8*)(&Kt[16 * t + lr][lh * 8]);
        #pragma unroll
        for (int od = 0; od < 2; ++od)
            #pragma unroll
            for (int ks = 0; ks < 2; ++ks)
                vf[od][ks] = *(const bf16x8*)(&Vl[od * 16 + lr][ks * 32 + lh * 8]);

        #pragma unroll
        for (int tq = 0; tq < 2; ++tq) {
            #pragma unroll
            for (int t = 0; t < 4; ++t) {
                // S^T sub-tile: A = K rows (m = key), B = Q (n = q)
                const f32x4 s = MFMA16(kf[t], qf[tq], zero);
                bf16x4 pb;
                float ss = 0.f;
                #pragma unroll
                for (int i = 0; i < 4; ++i) {
                    const float p = fast_exp2(s[i]);   // Q pre-scaled
                    ss += p;
                    pb[i] = (__bf16)p;
                }
                sacc[tq][t & 1] += ss;
                *(bf16x4*)(&Plds[wid][lr][16 * t + lh * 4]) = pb;
            }
            // per-wave P round-trip (must-alias, DS in-order per wave)
            const bf16x8 pa0 = *(const bf16x8*)(&Plds[wid][lr][lh * 8]);
            const bf16x8 pa1 = *(const bf16x8*)(&Plds[wid][lr][32 + lh * 8]);
            of[tq][0] = MFMA16(pa0, vf[0][0], of[tq][0]);
            of[tq][0] = MFMA16(pa1, vf[0][1], of[tq][0]);
            of[tq][1] = MFMA16(pa0, vf[1][0], of[tq][1]);
            of[tq][1] = MFMA16(pa1, vf[1][1], of[tq][1]);
        }

        __syncthreads();
    }

    const int b = bh >> 3, h = bh & 7;
    #pragma unroll
    for (int tq = 0; tq < 2; ++tq) {
        float sumw = sacc[tq][0] + sacc[tq][1];
        sumw += __shfl_xor(sumw, 16);
        sumw += __shfl_xor(sumw, 32);
        #pragma unroll
        for (int i = 0; i < 4; ++i) {
            const float rs = __shfl(sumw, lh * 4 + i);
            const float inv = 1.f / rs;
            const int row = q0 + tq * 16 + lh * 4 + i;
            const size_t base = ((size_t)b * L + row) * C + h * D;
            O[base + lr]      = (__bf16)(of[tq][0][i] * inv);
            O[base + 16 + lr] = (__bf16)(of[tq][1][i] * inv);
        }
    }
}

// ---------------------------------------------------------------------------
// Kernel 3: output projection. 64x64 tiles -> 512 blocks (2/CU), wave 32x32.
// ---------------------------------------------------------------------------
__global__ __launch_bounds__(256) void proj_gemm(
    const __bf16* __restrict__ A, const float* __restrict__ W,
    const float* __restrict__ Bp, float* __restrict__ Out)
{
    const int K = 256;
    const int bm = blockIdx.x & 127, bn = blockIdx.x >> 7;
    const int tid = threadIdx.x, wid = tid >> 6, lane = tid & 63;
    const int lr = lane & 15, lh = lane >> 4;
    const int m0 = bm * 64 + (wid >> 1) * 32;
    const int n0 = bn * 64 + (wid & 1) * 32;

    f32x4 acc[2][2] = {};
    const __bf16* Arow = A + (size_t)(m0 + lr) * K + lh * 8;
    const float*  Brow = W + (size_t)(n0 + lr) * K + lh * 8;

    #pragma unroll
    for (int k0 = 0; k0 < 256; k0 += 32) {
        bf16x8 a[2], b[2];
        #pragma unroll
        for (int mt = 0; mt < 2; ++mt) a[mt] = *(const bf16x8*)(Arow + mt * 16 * K + k0);
        #pragma unroll
        for (int nt = 0; nt < 2; ++nt) b[nt] = load_cvt8(Brow + nt * 16 * K + k0);
        #pragma unroll
        for (int mt = 0; mt < 2; ++mt)
            #pragma unroll
            for (int nt = 0; nt < 2; ++nt)
                acc[mt][nt] = MFMA16(a[mt], b[nt], acc[mt][nt]);
    }

    #pragma unroll
    for (int mt = 0; mt < 2; ++mt) {
        #pragma unroll
        for (int nt = 0; nt < 2; ++nt) {
            const int n = n0 + nt * 16 + lr;
            const float bias = Bp[n];
            #pragma unroll
            for (int i = 0; i < 4; ++i) {
                const int m = m0 + mt * 16 + lh * 4 + i;
                Out[(size_t)m * 256 + n] = acc[mt][nt][i] + bias;
            }
        }
    }
}

__global__ void fatal_flag(float* Out, int n, float v) {
    int i = blockIdx.x * blockDim.x + threadIdx.x;
    if (i < n) Out[i] = (i == 0) ? v : 0.f;
}

// ---------------------------------------------------------------------------
extern "C" void kernel_launch(void* const* d_in, const int* in_sizes, int n_in,
                              void* d_out, int out_size, void* d_ws, size_t ws_size,
                              hipStream_t stream)
{
    float* out = (float*)d_out;

    const float *x = nullptr, *w_qkv = nullptr, *b_qkv = nullptr,
                *w_proj = nullptr, *b_proj = nullptr;
    for (int i = 0; i < n_in; ++i) {
        switch (in_sizes[i]) {
            case 2097152: x      = (const float*)d_in[i]; break;
            case 196608:  w_qkv  = (const float*)d_in[i]; break;
            case 768:     b_qkv  = (const float*)d_in[i]; break;
            case 65536:   w_proj = (const float*)d_in[i]; break;
            case 256:     b_proj = (const float*)d_in[i]; break;
        }
    }
    if (!x || !w_qkv || !b_qkv || !w_proj || !b_proj) {
        fatal_flag<<<dim3((out_size + 255) / 256), dim3(256), 0, stream>>>(out, out_size, 3e9f);
        return;
    }

    const size_t SEG = (size_t)Bsz * H * L * D;      // 2M elems
    if (ws_size < 4 * SEG * sizeof(__bf16)) {
        fatal_flag<<<dim3((out_size + 255) / 256), dim3(256), 0, stream>>>(out, out_size, 1e9f);
        return;
    }

    __bf16* ws = (__bf16*)d_ws;
    __bf16* Qw = ws;
    __bf16* Kw = ws + SEG;
    __bf16* Vt = ws + 2 * SEG;
    __bf16* Ob = ws + 3 * SEG;

    qkv_gemm<<<dim3(768), dim3(256), 0, stream>>>(x, w_qkv, b_qkv, Qw, Kw, Vt);
    attn_fwd<<<dim3(512), dim3(256), 0, stream>>>(Qw, Kw, Vt, Ob);
    proj_gemm<<<dim3(512), dim3(256), 0, stream>>>(Ob, w_proj, b_proj, out);
}

// Round 17
// 67.604 us; speedup vs baseline: 1.3463x; 1.3463x over previous
//
#include <hip/hip_runtime.h>
#include <hip/hip_bf16.h>

// Problem: SelfAttention1d  B=4, L=2048, C=256, H=8, D=32.
// dtypes: inputs fp32, output fp32.
// ws layout (bf16): Q (B,H,L,D) | K (B,H,L,D) | Vt (B,H,D,L) | O (B,L,C) = 16MB.
// Round 17: (a) qkv: coalesced LDS staging of X/W tiles (per-lane fragment
// loads touched ~32 lines/instr -> request-rate bound; staged loads are
// dense); (b) attn: double-buffered K/V LDS + register prefetch issued
// before the single per-tile barrier (hides ~300cy staging latency).

typedef __bf16 bf16x4 __attribute__((ext_vector_type(4)));
typedef __bf16 bf16x8 __attribute__((ext_vector_type(8)));
typedef float  f32x4  __attribute__((ext_vector_type(4)));

#define MFMA16(a, b, c) __builtin_amdgcn_mfma_f32_16x16x32_bf16((a), (b), (c), 0, 0, 0)

static constexpr int Bsz = 4, L = 2048, C = 256, H = 8, D = 32;
static constexpr float SCALE = 0.17677669529663687f;   // 32^-0.5
static constexpr float LOG2E = 1.44269504088896f;
static constexpr float QSCALE = SCALE * LOG2E;         // exp2(S) = softmax exp

__device__ inline float fast_exp2(float x) {
#if __has_builtin(__builtin_amdgcn_exp2f)
    return __builtin_amdgcn_exp2f(x);
#else
    float r; asm("v_exp_f32 %0, %1" : "=v"(r) : "v"(x)); return r;
#endif
}

// ---------------------------------------------------------------------------
// Kernel 1: QKV GEMM with coalesced LDS staging.
// grid 768 = 64 bm x 12 bn, 256 thr (4 waves, 2x2 wave grid, wave tile 64x32).
// K processed in 2 chunks of 128: stage X-chunk(128x128) + W-chunk(64x128)
// as bf16 in LDS (dense f32x4 global loads: 2 rows/instr, full lines), then
// MFMA from LDS fragments. Epilogue scratch aliases staging LDS.
// ---------------------------------------------------------------------------
__global__ __launch_bounds__(256) void qkv_gemm(
    const float* __restrict__ X, const float* __restrict__ W,
    const float* __restrict__ Bq,
    __bf16* __restrict__ Qw, __bf16* __restrict__ Kw, __bf16* __restrict__ Vt)
{
    constexpr int LDK = 136;                       // chunk-row stride (272B)
    __shared__ __align__(16) __bf16 smem[128 * LDK + 64 * LDK];  // 52224 B
    __bf16* Xs = smem;                             // [128][LDK]
    __bf16* Wsh = smem + 128 * LDK;                // [64][LDK]

    const int bm = blockIdx.x & 63, bn = blockIdx.x >> 6;
    const int tid = threadIdx.x, wid = tid >> 6, lane = tid & 63;
    const int lr = lane & 15, lh = lane >> 4;
    const int m0b = bm * 128, n0b = bn * 64;
    const int wm0 = (wid >> 1) * 64, wn0 = (wid & 1) * 32;

    const int srow2 = lane >> 5;                   // 0/1: which of 2 rows
    const int scol  = (lane & 31) * 4;             // f32 col within chunk

    f32x4 acc[4][2] = {};

    #pragma unroll
    for (int c = 0; c < 2; ++c) {
        const int k0c = c * 128;
        // ---- stage X chunk: 128 rows x 128 f32 -> bf16 ----
        #pragma unroll
        for (int j = 0; j < 16; ++j) {
            const int row = j * 8 + wid * 2 + srow2;
            const f32x4 v = *(const f32x4*)(X + (size_t)(m0b + row) * 256 + k0c + scol);
            bf16x4 cv; cv[0]=(__bf16)v[0]; cv[1]=(__bf16)v[1]; cv[2]=(__bf16)v[2]; cv[3]=(__bf16)v[3];
            *(bf16x4*)(&Xs[row * LDK + scol]) = cv;
        }
        // ---- stage W chunk: 64 rows x 128 f32 -> bf16 ----
        #pragma unroll
        for (int j = 0; j < 8; ++j) {
            const int row = j * 8 + wid * 2 + srow2;
            const f32x4 v = *(const f32x4*)(W + (size_t)(n0b + row) * 256 + k0c + scol);
            bf16x4 cv; cv[0]=(__bf16)v[0]; cv[1]=(__bf16)v[1]; cv[2]=(__bf16)v[2]; cv[3]=(__bf16)v[3];
            *(bf16x4*)(&Wsh[row * LDK + scol]) = cv;
        }
        __syncthreads();

        // ---- compute chunk: 4 k-steps of 32 ----
        #pragma unroll
        for (int ks = 0; ks < 4; ++ks) {
            bf16x8 a[4], b[2];
            #pragma unroll
            for (int mt = 0; mt < 4; ++mt)
                a[mt] = *(const bf16x8*)(&Xs[(wm0 + mt * 16 + lr) * LDK + ks * 32 + lh * 8]);
            #pragma unroll
            for (int nt = 0; nt < 2; ++nt)
                b[nt] = *(const bf16x8*)(&Wsh[(wn0 + nt * 16 + lr) * LDK + ks * 32 + lh * 8]);
            #pragma unroll
            for (int mt = 0; mt < 4; ++mt)
                #pragma unroll
                for (int nt = 0; nt < 2; ++nt)
                    acc[mt][nt] = MFMA16(a[mt], b[nt], acc[mt][nt]);
        }
        __syncthreads();                           // reads done before restage
    }

    // ---- epilogue (r16-proven): per-wave LDS scratch (aliases staging) ----
    const int m0 = m0b + wm0;
    const int n0 = n0b + wn0;
    const int bb  = m0 >> 11;
    const int li0 = m0 & 2047;
    const int h = n0 / 96, r = n0 % 96;
    const int which = r >> 5;                      // 0=Q 1=K 2=V
    const int bh = bb * H + h;
    __bf16* sw = smem + wid * 2560;

    if (which == 2) {
        #pragma unroll
        for (int nt = 0; nt < 2; ++nt) {
            const float bias = Bq[n0 + nt * 16 + lr];
            #pragma unroll
            for (int mt = 0; mt < 4; ++mt)
                #pragma unroll
                for (int i = 0; i < 4; ++i)
                    sw[(nt * 16 + lr) * 72 + mt * 16 + lh * 4 + i] =
                        (__bf16)(acc[mt][nt][i] + bias);
        }
        #pragma unroll
        for (int j = 0; j < 4; ++j) {
            const int cch = lane + 64 * j;
            const int d = cch >> 3, lc = (cch & 7) * 8;
            const bf16x8 v = *(const bf16x8*)(&sw[d * 72 + lc]);
            *(bf16x8*)(Vt + ((size_t)bh * D + d) * L + li0 + lc) = v;
        }
    } else {
        const float scl = (which == 0) ? QSCALE : 1.0f;
        #pragma unroll
        for (int nt = 0; nt < 2; ++nt) {
            const float bias = Bq[n0 + nt * 16 + lr];
            #pragma unroll
            for (int mt = 0; mt < 4; ++mt)
                #pragma unroll
                for (int i = 0; i < 4; ++i)
                    sw[(mt * 16 + lh * 4 + i) * 40 + nt * 16 + lr] =
                        (__bf16)((acc[mt][nt][i] + bias) * scl);
        }
        __bf16* dst = (which == 0 ? Qw : Kw) + ((size_t)bh * L + li0) * D;
        #pragma unroll
        for (int j = 0; j < 4; ++j) {
            const int cch = lane + 64 * j;
            const bf16x8 v = *(const bf16x8*)(&sw[(cch >> 2) * 40 + (cch & 3) * 8]);
            *(bf16x8*)(dst + (size_t)cch * 8) = v;
        }
    }
}

// ---------------------------------------------------------------------------
// Kernel 2: flash attention, double-buffered K/V LDS, 1 barrier/tile,
// register prefetch issued before the barrier. grid 512 x 256 thr (4 waves),
// wave = 32 q-rows. Sum-softmax (exp2, Q pre-scaled).
// ---------------------------------------------------------------------------
__global__ __launch_bounds__(256, 2) void attn_fwd(
    const __bf16* __restrict__ Qw, const __bf16* __restrict__ Kw,
    const __bf16* __restrict__ Vt, __bf16* __restrict__ O)
{
    __shared__ __align__(16) __bf16 Kt[2][64][40];
    __shared__ __align__(16) __bf16 Vl[2][32][72];
    __shared__ __align__(16) __bf16 Plds[4][16][72];

    const int bid = blockIdx.x;
    const int bh = ((bid & 7) << 2) | ((bid >> 3) & 3);
    const int qt = bid >> 5;
    const int tid = threadIdx.x, wid = tid >> 6, lane = tid & 63;
    const int lr = lane & 15, lh = lane >> 4;
    const int q0 = qt * 128 + wid * 32;

    const __bf16* Qb = Qw + (size_t)bh * L * D;
    const __bf16* Kb = Kw + (size_t)bh * L * D;
    const __bf16* Vb = Vt + (size_t)bh * D * L;

    bf16x8 qf[2];
    #pragma unroll
    for (int tq = 0; tq < 2; ++tq)
        qf[tq] = *(const bf16x8*)(Qb + (size_t)(q0 + tq * 16 + lr) * D + lh * 8);

    f32x4 of[2][2] = {};
    float sacc[2][2] = {};
    const f32x4 zero = {0.f, 0.f, 0.f, 0.f};

    const int t128 = ((wid & 1) << 6) | lane;
    const int kr = t128 >> 1, kc = (t128 & 1) * 16;
    const int vr = t128 >> 2, vc = (t128 & 3) * 16;

    bf16x8 sA, sB;                                  // prefetch registers
#define LOADR(KV) do {                                                        \
    if (wid < 2) {                                                            \
        sA = *(const bf16x8*)(Kb + (size_t)((KV) + kr) * D + kc);             \
        sB = *(const bf16x8*)(Kb + (size_t)((KV) + kr) * D + kc + 8);         \
    } else {                                                                  \
        sA = *(const bf16x8*)(Vb + (size_t)vr * L + (KV) + vc);               \
        sB = *(const bf16x8*)(Vb + (size_t)vr * L + (KV) + vc + 8);           \
    }                                                                         \
} while (0)
#define WRITEB(BUF) do {                                                      \
    if (wid < 2) {                                                            \
        *(bf16x8*)(&Kt[BUF][kr][kc])     = sA;                                \
        *(bf16x8*)(&Kt[BUF][kr][kc + 8]) = sB;                                \
    } else {                                                                  \
        *(bf16x8*)(&Vl[BUF][vr][vc])     = sA;                                \
        *(bf16x8*)(&Vl[BUF][vr][vc + 8]) = sB;                                \
    }                                                                         \
} while (0)

    LOADR(0);
    WRITEB(0);

    for (int t = 0; t < 32; ++t) {
        const int cur = t & 1;
        if (t + 1 < 32) LOADR((t + 1) * 64);       // issue early: hides under compute
        __syncthreads();                            // buf[cur] visible

        bf16x8 kf[4], vf[2][2];
        #pragma unroll
        for (int u = 0; u < 4; ++u)
            kf[u] = *(const bf16x8*)(&Kt[cur][16 * u + lr][lh * 8]);
        #pragma unroll
        for (int od = 0; od < 2; ++od)
            #pragma unroll
            for (int ks = 0; ks < 2; ++ks)
                vf[od][ks] = *(const bf16x8*)(&Vl[cur][od * 16 + lr][ks * 32 + lh * 8]);

        #pragma unroll
        for (int tq = 0; tq < 2; ++tq) {
            #pragma unroll
            for (int u = 0; u < 4; ++u) {
                // S^T sub-tile: A = K rows (m = key), B = Q (n = q)
                const f32x4 s = MFMA16(kf[u], qf[tq], zero);
                bf16x4 pb;
                float ss = 0.f;
                #pragma unroll
                for (int i = 0; i < 4; ++i) {
                    const float p = fast_exp2(s[i]);   // Q pre-scaled
                    ss += p;
                    pb[i] = (__bf16)p;
                }
                sacc[tq][u & 1] += ss;
                *(bf16x4*)(&Plds[wid][lr][16 * u + lh * 4]) = pb;
            }
            // per-wave P round-trip (must-alias, DS in-order per wave)
            const bf16x8 pa0 = *(const bf16x8*)(&Plds[wid][lr][lh * 8]);
            const bf16x8 pa1 = *(const bf16x8*)(&Plds[wid][lr][32 + lh * 8]);
            of[tq][0] = MFMA16(pa0, vf[0][0], of[tq][0]);
            of[tq][0] = MFMA16(pa1, vf[0][1], of[tq][0]);
            of[tq][1] = MFMA16(pa0, vf[1][0], of[tq][1]);
            of[tq][1] = MFMA16(pa1, vf[1][1], of[tq][1]);
        }

        if (t + 1 < 32) WRITEB(cur ^ 1);           // land prefetch in other buffer
    }
#undef LOADR
#undef WRITEB

    const int b = bh >> 3, h = bh & 7;
    #pragma unroll
    for (int tq = 0; tq < 2; ++tq) {
        float sumw = sacc[tq][0] + sacc[tq][1];
        sumw += __shfl_xor(sumw, 16);
        sumw += __shfl_xor(sumw, 32);
        #pragma unroll
        for (int i = 0; i < 4; ++i) {
            const float rs = __shfl(sumw, lh * 4 + i);
            const float inv = 1.f / rs;
            const int row = q0 + tq * 16 + lh * 4 + i;
            const size_t base = ((size_t)b * L + row) * C + h * D;
            O[base + lr]      = (__bf16)(of[tq][0][i] * inv);
            O[base + 16 + lr] = (__bf16)(of[tq][1][i] * inv);
        }
    }
}

// ---------------------------------------------------------------------------
// Kernel 3: output projection. 64x64 tiles -> 512 blocks, wave 32x32.
// ---------------------------------------------------------------------------
__global__ __launch_bounds__(256) void proj_gemm(
    const __bf16* __restrict__ A, const float* __restrict__ W,
    const float* __restrict__ Bp, float* __restrict__ Out)
{
    const int K = 256;
    const int bm = blockIdx.x & 127, bn = blockIdx.x >> 7;
    const int tid = threadIdx.x, wid = tid >> 6, lane = tid & 63;
    const int lr = lane & 15, lh = lane >> 4;
    const int m0 = bm * 64 + (wid >> 1) * 32;
    const int n0 = bn * 64 + (wid & 1) * 32;

    f32x4 acc[2][2] = {};
    const __bf16* Arow = A + (size_t)(m0 + lr) * K + lh * 8;
    const float*  Brow = W + (size_t)(n0 + lr) * K + lh * 8;

    #pragma unroll
    for (int k0 = 0; k0 < 256; k0 += 32) {
        bf16x8 a[2], b[2];
        #pragma unroll
        for (int mt = 0; mt < 2; ++mt) a[mt] = *(const bf16x8*)(Arow + mt * 16 * K + k0);
        #pragma unroll
        for (int nt = 0; nt < 2; ++nt) {
            const f32x4 v0 = *(const f32x4*)(Brow + nt * 16 * K + k0);
            const f32x4 v1 = *(const f32x4*)(Brow + nt * 16 * K + k0 + 4);
            bf16x8 bb;
            bb[0]=(__bf16)v0[0]; bb[1]=(__bf16)v0[1]; bb[2]=(__bf16)v0[2]; bb[3]=(__bf16)v0[3];
            bb[4]=(__bf16)v1[0]; bb[5]=(__bf16)v1[1]; bb[6]=(__bf16)v1[2]; bb[7]=(__bf16)v1[3];
            b[nt] = bb;
        }
        #pragma unroll
        for (int mt = 0; mt < 2; ++mt)
            #pragma unroll
            for (int nt = 0; nt < 2; ++nt)
                acc[mt][nt] = MFMA16(a[mt], b[nt], acc[mt][nt]);
    }

    #pragma unroll
    for (int mt = 0; mt < 2; ++mt) {
        #pragma unroll
        for (int nt = 0; nt < 2; ++nt) {
            const int n = n0 + nt * 16 + lr;
            const float bias = Bp[n];
            #pragma unroll
            for (int i = 0; i < 4; ++i) {
                const int m = m0 + mt * 16 + lh * 4 + i;
                Out[(size_t)m * 256 + n] = acc[mt][nt][i] + bias;
            }
        }
    }
}

__global__ void fatal_flag(float* Out, int n, float v) {
    int i = blockIdx.x * blockDim.x + threadIdx.x;
    if (i < n) Out[i] = (i == 0) ? v : 0.f;
}

// ---------------------------------------------------------------------------
extern "C" void kernel_launch(void* const* d_in, const int* in_sizes, int n_in,
                              void* d_out, int out_size, void* d_ws, size_t ws_size,
                              hipStream_t stream)
{
    float* out = (float*)d_out;

    const float *x = nullptr, *w_qkv = nullptr, *b_qkv = nullptr,
                *w_proj = nullptr, *b_proj = nullptr;
    for (int i = 0; i < n_in; ++i) {
        switch (in_sizes[i]) {
            case 2097152: x      = (const float*)d_in[i]; break;
            case 196608:  w_qkv  = (const float*)d_in[i]; break;
            case 768:     b_qkv  = (const float*)d_in[i]; break;
            case 65536:   w_proj = (const float*)d_in[i]; break;
            case 256:     b_proj = (const float*)d_in[i]; break;
        }
    }
    if (!x || !w_qkv || !b_qkv || !w_proj || !b_proj) {
        fatal_flag<<<dim3((out_size + 255) / 256), dim3(256), 0, stream>>>(out, out_size, 3e9f);
        return;
    }

    const size_t SEG = (size_t)Bsz * H * L * D;      // 2M elems
    if (ws_size < 4 * SEG * sizeof(__bf16)) {
        fatal_flag<<<dim3((out_size + 255) / 256), dim3(256), 0, stream>>>(out, out_size, 1e9f);
        return;
    }

    __bf16* ws = (__bf16*)d_ws;
    __bf16* Qw = ws;
    __bf16* Kw = ws + SEG;
    __bf16* Vt = ws + 2 * SEG;
    __bf16* Ob = ws + 3 * SEG;

    qkv_gemm<<<dim3(768), dim3(256), 0, stream>>>(x, w_qkv, b_qkv, Qw, Kw, Vt);
    attn_fwd<<<dim3(512), dim3(256), 0, stream>>>(Qw, Kw, Vt, Ob);
    proj_gemm<<<dim3(512), dim3(256), 0, stream>>>(Ob, w_proj, b_proj, out);
}

// Round 18
// 63.650 us; speedup vs baseline: 1.4299x; 1.0621x over previous
//
#include <hip/hip_runtime.h>
#include <hip/hip_bf16.h>

// Problem: SelfAttention1d  B=4, L=2048, C=256, H=8, D=32.
// dtypes: inputs fp32, output fp32 (r17 = 67.6us: attn ~30, qkv ~17, proj ~9).
// Round 18: attn -> 32x32x16 MFMA + in-register P relayout (cvt_pk +
// v_permlane32_swap_b32, T12): P LDS round-trip (12 of 22 LDS ops/tile/wave)
// deleted; 32 q/wave in one C tile. qkv/proj unchanged from r17.

typedef __bf16 bf16x4 __attribute__((ext_vector_type(4)));
typedef __bf16 bf16x8 __attribute__((ext_vector_type(8)));
typedef float  f32x4  __attribute__((ext_vector_type(4)));
typedef float  f32x16 __attribute__((ext_vector_type(16)));
typedef unsigned u32x4 __attribute__((ext_vector_type(4)));

#define MFMA16(a, b, c) __builtin_amdgcn_mfma_f32_16x16x32_bf16((a), (b), (c), 0, 0, 0)
#define MFMA32(a, b, c) __builtin_amdgcn_mfma_f32_32x32x16_bf16((a), (b), (c), 0, 0, 0)

static constexpr int Bsz = 4, L = 2048, C = 256, H = 8, D = 32;
static constexpr float SCALE = 0.17677669529663687f;   // 32^-0.5
static constexpr float LOG2E = 1.44269504088896f;
static constexpr float QSCALE = SCALE * LOG2E;         // exp2(S) = softmax exp

__device__ inline float fast_exp2(float x) {
#if __has_builtin(__builtin_amdgcn_exp2f)
    return __builtin_amdgcn_exp2f(x);
#else
    float r; asm("v_exp_f32 %0, %1" : "=v"(r) : "v"(x)); return r;
#endif
}

__device__ inline unsigned cvt_pk_bf16(float lo, float hi) {
    unsigned d;
    asm("v_cvt_pk_bf16_f32 %0, %1, %2" : "=v"(d) : "v"(lo), "v"(hi));
    return d;
}

// ---------------------------------------------------------------------------
// Kernel 1: QKV GEMM with coalesced LDS staging (r17, unchanged).
// ---------------------------------------------------------------------------
__global__ __launch_bounds__(256) void qkv_gemm(
    const float* __restrict__ X, const float* __restrict__ W,
    const float* __restrict__ Bq,
    __bf16* __restrict__ Qw, __bf16* __restrict__ Kw, __bf16* __restrict__ Vt)
{
    constexpr int LDK = 136;
    __shared__ __align__(16) __bf16 smem[128 * LDK + 64 * LDK];
    __bf16* Xs = smem;
    __bf16* Wsh = smem + 128 * LDK;

    const int bm = blockIdx.x & 63, bn = blockIdx.x >> 6;
    const int tid = threadIdx.x, wid = tid >> 6, lane = tid & 63;
    const int lr = lane & 15, lh = lane >> 4;
    const int m0b = bm * 128, n0b = bn * 64;
    const int wm0 = (wid >> 1) * 64, wn0 = (wid & 1) * 32;

    const int srow2 = lane >> 5;
    const int scol  = (lane & 31) * 4;

    f32x4 acc[4][2] = {};

    #pragma unroll
    for (int c = 0; c < 2; ++c) {
        const int k0c = c * 128;
        #pragma unroll
        for (int j = 0; j < 16; ++j) {
            const int row = j * 8 + wid * 2 + srow2;
            const f32x4 v = *(const f32x4*)(X + (size_t)(m0b + row) * 256 + k0c + scol);
            bf16x4 cv; cv[0]=(__bf16)v[0]; cv[1]=(__bf16)v[1]; cv[2]=(__bf16)v[2]; cv[3]=(__bf16)v[3];
            *(bf16x4*)(&Xs[row * LDK + scol]) = cv;
        }
        #pragma unroll
        for (int j = 0; j < 8; ++j) {
            const int row = j * 8 + wid * 2 + srow2;
            const f32x4 v = *(const f32x4*)(W + (size_t)(n0b + row) * 256 + k0c + scol);
            bf16x4 cv; cv[0]=(__bf16)v[0]; cv[1]=(__bf16)v[1]; cv[2]=(__bf16)v[2]; cv[3]=(__bf16)v[3];
            *(bf16x4*)(&Wsh[row * LDK + scol]) = cv;
        }
        __syncthreads();

        #pragma unroll
        for (int ks = 0; ks < 4; ++ks) {
            bf16x8 a[4], b[2];
            #pragma unroll
            for (int mt = 0; mt < 4; ++mt)
                a[mt] = *(const bf16x8*)(&Xs[(wm0 + mt * 16 + lr) * LDK + ks * 32 + lh * 8]);
            #pragma unroll
            for (int nt = 0; nt < 2; ++nt)
                b[nt] = *(const bf16x8*)(&Wsh[(wn0 + nt * 16 + lr) * LDK + ks * 32 + lh * 8]);
            #pragma unroll
            for (int mt = 0; mt < 4; ++mt)
                #pragma unroll
                for (int nt = 0; nt < 2; ++nt)
                    acc[mt][nt] = MFMA16(a[mt], b[nt], acc[mt][nt]);
        }
        __syncthreads();
    }

    const int m0 = m0b + wm0;
    const int n0 = n0b + wn0;
    const int bb  = m0 >> 11;
    const int li0 = m0 & 2047;
    const int h = n0 / 96, r = n0 % 96;
    const int which = r >> 5;
    const int bh = bb * H + h;
    __bf16* sw = smem + wid * 2560;

    if (which == 2) {
        #pragma unroll
        for (int nt = 0; nt < 2; ++nt) {
            const float bias = Bq[n0 + nt * 16 + lr];
            #pragma unroll
            for (int mt = 0; mt < 4; ++mt)
                #pragma unroll
                for (int i = 0; i < 4; ++i)
                    sw[(nt * 16 + lr) * 72 + mt * 16 + lh * 4 + i] =
                        (__bf16)(acc[mt][nt][i] + bias);
        }
        #pragma unroll
        for (int j = 0; j < 4; ++j) {
            const int cch = lane + 64 * j;
            const int d = cch >> 3, lc = (cch & 7) * 8;
            const bf16x8 v = *(const bf16x8*)(&sw[d * 72 + lc]);
            *(bf16x8*)(Vt + ((size_t)bh * D + d) * L + li0 + lc) = v;
        }
    } else {
        const float scl = (which == 0) ? QSCALE : 1.0f;
        #pragma unroll
        for (int nt = 0; nt < 2; ++nt) {
            const float bias = Bq[n0 + nt * 16 + lr];
            #pragma unroll
            for (int mt = 0; mt < 4; ++mt)
                #pragma unroll
                for (int i = 0; i < 4; ++i)
                    sw[(mt * 16 + lh * 4 + i) * 40 + nt * 16 + lr] =
                        (__bf16)((acc[mt][nt][i] + bias) * scl);
        }
        __bf16* dst = (which == 0 ? Qw : Kw) + ((size_t)bh * L + li0) * D;
        #pragma unroll
        for (int j = 0; j < 4; ++j) {
            const int cch = lane + 64 * j;
            const bf16x8 v = *(const bf16x8*)(&sw[(cch >> 2) * 40 + (cch & 3) * 8]);
            *(bf16x8*)(dst + (size_t)cch * 8) = v;
        }
    }
}

// ---------------------------------------------------------------------------
// Kernel 2: flash attention, 32x32x16 MFMA + in-register P relayout.
// grid 512 x 256 thr (4 waves x 32 q-rows). K/V double-buffered in LDS
// (r17 prefetch structure). Per 64-key tile: 2 subtiles of 32 keys.
// Swapped QK^T: S^T[key][q]; softmax P stays in registers: cvt_pk pairs +
// v_permlane32_swap_b32 build the PV A-operand directly (T12).
// ---------------------------------------------------------------------------
__global__ __launch_bounds__(256, 2) void attn_fwd(
    const __bf16* __restrict__ Qw, const __bf16* __restrict__ Kw,
    const __bf16* __restrict__ Vt, __bf16* __restrict__ O)
{
    __shared__ __align__(16) __bf16 Kt[2][64][40];
    __shared__ __align__(16) __bf16 Vl[2][32][72];

    const int bid = blockIdx.x;
    const int bh = ((bid & 7) << 2) | ((bid >> 3) & 3);
    const int qt = bid >> 5;
    const int tid = threadIdx.x, wid = tid >> 6, lane = tid & 63;
    const int lo = lane & 31, hi = lane >> 5;
    const int q0 = qt * 128 + wid * 32;

    const __bf16* Qb = Qw + (size_t)bh * L * D;
    const __bf16* Kb = Kw + (size_t)bh * L * D;
    const __bf16* Vb = Vt + (size_t)bh * D * L;

    // Q B-operand frags: B[n=q=lo][k=d=call*16 + hi*8 + j]
    bf16x8 qf[2];
    #pragma unroll
    for (int cl = 0; cl < 2; ++cl)
        qf[cl] = *(const bf16x8*)(Qb + (size_t)(q0 + lo) * D + cl * 16 + hi * 8);

    f32x16 oacc = {};
    float sacc[4] = {0.f, 0.f, 0.f, 0.f};

    const int t128 = ((wid & 1) << 6) | lane;
    const int kr = t128 >> 1, kc = (t128 & 1) * 16;
    const int vr = t128 >> 2, vc = (t128 & 3) * 16;

    bf16x8 sA, sB;
#define LOADR(KV) do {                                                        \
    if (wid < 2) {                                                            \
        sA = *(const bf16x8*)(Kb + (size_t)((KV) + kr) * D + kc);             \
        sB = *(const bf16x8*)(Kb + (size_t)((KV) + kr) * D + kc + 8);         \
    } else {                                                                  \
        sA = *(const bf16x8*)(Vb + (size_t)vr * L + (KV) + vc);               \
        sB = *(const bf16x8*)(Vb + (size_t)vr * L + (KV) + vc + 8);           \
    }                                                                         \
} while (0)
#define WRITEB(BUF) do {                                                      \
    if (wid < 2) {                                                            \
        *(bf16x8*)(&Kt[BUF][kr][kc])     = sA;                                \
        *(bf16x8*)(&Kt[BUF][kr][kc + 8]) = sB;                                \
    } else {                                                                  \
        *(bf16x8*)(&Vl[BUF][vr][vc])     = sA;                                \
        *(bf16x8*)(&Vl[BUF][vr][vc + 8]) = sB;                                \
    }                                                                         \
} while (0)

    LOADR(0);
    WRITEB(0);

    for (int t = 0; t < 32; ++t) {
        const int cur = t & 1;
        if (t + 1 < 32) LOADR((t + 1) * 64);
        __syncthreads();

        #pragma unroll
        for (int sub = 0; sub < 2; ++sub) {
            const int kb = sub * 32;

            // QK^T: A = K rows (m=key=lo), k-dim = d (2 calls of 16)
            f32x16 sst = {};
            const bf16x8 ka0 = *(const bf16x8*)(&Kt[cur][kb + lo][hi * 8]);
            const bf16x8 ka1 = *(const bf16x8*)(&Kt[cur][kb + lo][16 + hi * 8]);
            sst = MFMA32(ka0, qf[0], sst);
            sst = MFMA32(ka1, qf[1], sst);

            // softmax numerators, in-register (Q pre-scaled by SCALE*LOG2E)
            float p[16];
            #pragma unroll
            for (int r = 0; r < 16; ++r) p[r] = fast_exp2(sst[r]);
            #pragma unroll
            for (int r = 0; r < 16; ++r) sacc[r & 3] += p[r];

            unsigned pk[8];
            #pragma unroll
            for (int j = 0; j < 8; ++j) pk[j] = cvt_pk_bf16(p[2 * j], p[2 * j + 1]);

            // P relayout: key rows (r&3)+8(r>>2)+4hi -> A-operand k=hi*8+j.
            // swap(P_A,P_B) & swap(P_C,P_D): one swap fills two frag dwords.
            unsigned a0 = pk[0], b0 = pk[2];
            unsigned a1 = pk[1], b1 = pk[3];
            unsigned c0 = pk[4], d0 = pk[6];
            unsigned c1 = pk[5], d1 = pk[7];
            asm("v_permlane32_swap_b32 %0, %1" : "+v"(a0), "+v"(b0));
            asm("v_permlane32_swap_b32 %0, %1" : "+v"(a1), "+v"(b1));
            asm("v_permlane32_swap_b32 %0, %1" : "+v"(c0), "+v"(d0));
            asm("v_permlane32_swap_b32 %0, %1" : "+v"(c1), "+v"(d1));
            const u32x4 f0 = {a0, a1, b0, b1};
            const u32x4 f1 = {c0, c1, d0, d1};
            const bf16x8 pf0 = __builtin_bit_cast(bf16x8, f0);
            const bf16x8 pf1 = __builtin_bit_cast(bf16x8, f1);

            // PV: A = P (m=q, k=key), B = V^T (n=d=lo, k=key)
            const bf16x8 vb0 = *(const bf16x8*)(&Vl[cur][lo][kb + hi * 8]);
            const bf16x8 vb1 = *(const bf16x8*)(&Vl[cur][lo][kb + 16 + hi * 8]);
            oacc = MFMA32(pf0, vb0, oacc);
            oacc = MFMA32(pf1, vb1, oacc);
        }

        if (t + 1 < 32) WRITEB(cur ^ 1);
    }
#undef LOADR
#undef WRITEB

    // per-q sum: lane's 16 p's cover its hi-half keys; combine halves
    float tot = (sacc[0] + sacc[1]) + (sacc[2] + sacc[3]);
    tot += __shfl_xor(tot, 32);
    const float inv = 1.f / tot;                 // for q = lo (both halves)

    const int b = bh >> 3, h = bh & 7;
    #pragma unroll
    for (int r = 0; r < 16; ++r) {
        const int qr = (r & 3) + 8 * (r >> 2) + 4 * hi;
        const float rs = __shfl(inv, qr);        // lane qr holds q=qr's inv
        const int row = q0 + qr;
        O[((size_t)b * L + row) * C + h * D + lo] = (__bf16)(oacc[r] * rs);
    }
}

// ---------------------------------------------------------------------------
// Kernel 3: output projection (r17, unchanged). 64x64 tiles, 512 blocks.
// ---------------------------------------------------------------------------
__global__ __launch_bounds__(256) void proj_gemm(
    const __bf16* __restrict__ A, const float* __restrict__ W,
    const float* __restrict__ Bp, float* __restrict__ Out)
{
    const int K = 256;
    const int bm = blockIdx.x & 127, bn = blockIdx.x >> 7;
    const int tid = threadIdx.x, wid = tid >> 6, lane = tid & 63;
    const int lr = lane & 15, lh = lane >> 4;
    const int m0 = bm * 64 + (wid >> 1) * 32;
    const int n0 = bn * 64 + (wid & 1) * 32;

    f32x4 acc[2][2] = {};
    const __bf16* Arow = A + (size_t)(m0 + lr) * K + lh * 8;
    const float*  Brow = W + (size_t)(n0 + lr) * K + lh * 8;

    #pragma unroll
    for (int k0 = 0; k0 < 256; k0 += 32) {
        bf16x8 a[2], b[2];
        #pragma unroll
        for (int mt = 0; mt < 2; ++mt) a[mt] = *(const bf16x8*)(Arow + mt * 16 * K + k0);
        #pragma unroll
        for (int nt = 0; nt < 2; ++nt) {
            const f32x4 v0 = *(const f32x4*)(Brow + nt * 16 * K + k0);
            const f32x4 v1 = *(const f32x4*)(Brow + nt * 16 * K + k0 + 4);
            bf16x8 bb;
            bb[0]=(__bf16)v0[0]; bb[1]=(__bf16)v0[1]; bb[2]=(__bf16)v0[2]; bb[3]=(__bf16)v0[3];
            bb[4]=(__bf16)v1[0]; bb[5]=(__bf16)v1[1]; bb[6]=(__bf16)v1[2]; bb[7]=(__bf16)v1[3];
            b[nt] = bb;
        }
        #pragma unroll
        for (int mt = 0; mt < 2; ++mt)
            #pragma unroll
            for (int nt = 0; nt < 2; ++nt)
                acc[mt][nt] = MFMA16(a[mt], b[nt], acc[mt][nt]);
    }

    #pragma unroll
    for (int mt = 0; mt < 2; ++mt) {
        #pragma unroll
        for (int nt = 0; nt < 2; ++nt) {
            const int n = n0 + nt * 16 + lr;
            const float bias = Bp[n];
            #pragma unroll
            for (int i = 0; i < 4; ++i) {
                const int m = m0 + mt * 16 + lh * 4 + i;
                Out[(size_t)m * 256 + n] = acc[mt][nt][i] + bias;
            }
        }
    }
}

__global__ void fatal_flag(float* Out, int n, float v) {
    int i = blockIdx.x * blockDim.x + threadIdx.x;
    if (i < n) Out[i] = (i == 0) ? v : 0.f;
}

// ---------------------------------------------------------------------------
extern "C" void kernel_launch(void* const* d_in, const int* in_sizes, int n_in,
                              void* d_out, int out_size, void* d_ws, size_t ws_size,
                              hipStream_t stream)
{
    float* out = (float*)d_out;

    const float *x = nullptr, *w_qkv = nullptr, *b_qkv = nullptr,
                *w_proj = nullptr, *b_proj = nullptr;
    for (int i = 0; i < n_in; ++i) {
        switch (in_sizes[i]) {
            case 2097152: x      = (const float*)d_in[i]; break;
            case 196608:  w_qkv  = (const float*)d_in[i]; break;
            case 768:     b_qkv  = (const float*)d_in[i]; break;
            case 65536:   w_proj = (const float*)d_in[i]; break;
            case 256:     b_proj = (const float*)d_in[i]; break;
        }
    }
    if (!x || !w_qkv || !b_qkv || !w_proj || !b_proj) {
        fatal_flag<<<dim3((out_size + 255) / 256), dim3(256), 0, stream>>>(out, out_size, 3e9f);
        return;
    }

    const size_t SEG = (size_t)Bsz * H * L * D;      // 2M elems
    if (ws_size < 4 * SEG * sizeof(__bf16)) {
        fatal_flag<<<dim3((out_size + 255) / 256), dim3(256), 0, stream>>>(out, out_size, 1e9f);
        return;
    }

    __bf16* ws = (__bf16*)d_ws;
    __bf16* Qw = ws;
    __bf16* Kw = ws + SEG;
    __bf16* Vt = ws + 2 * SEG;
    __bf16* Ob = ws + 3 * SEG;

    qkv_gemm<<<dim3(768), dim3(256), 0, stream>>>(x, w_qkv, b_qkv, Qw, Kw, Vt);
    attn_fwd<<<dim3(512), dim3(256), 0, stream>>>(Qw, Kw, Vt, Ob);
    proj_gemm<<<dim3(512), dim3(256), 0, stream>>>(Ob, w_proj, b_proj, out);
}

// Round 19
// 57.824 us; speedup vs baseline: 1.5740x; 1.1008x over previous
//
#include <hip/hip_runtime.h>
#include <hip/hip_bf16.h>

// Problem: SelfAttention1d  B=4, L=2048, C=256, H=8, D=32.
// dtypes: inputs fp32, output fp32 (r18 = 63.65us; attn ~26, qkv ~17, proj ~9).
// Round 19: (1) attn KV-split 2: grid 1024, wave = (qgroup, khalf) -> 32 q x
// 1024 keys; 4 waves/SIMD (was grid-capped at 2); LDS flattened to 38KB
// (4 blocks/CU), combine buffer aliases staging; (2) proj: dense LDS staging
// of A/W (same request-amplification fix as qkv r17).

typedef __bf16 bf16x4 __attribute__((ext_vector_type(4)));
typedef __bf16 bf16x8 __attribute__((ext_vector_type(8)));
typedef float  f32x4  __attribute__((ext_vector_type(4)));
typedef float  f32x16 __attribute__((ext_vector_type(16)));
typedef unsigned u32x4 __attribute__((ext_vector_type(4)));

#define MFMA16(a, b, c) __builtin_amdgcn_mfma_f32_16x16x32_bf16((a), (b), (c), 0, 0, 0)
#define MFMA32(a, b, c) __builtin_amdgcn_mfma_f32_32x32x16_bf16((a), (b), (c), 0, 0, 0)

static constexpr int Bsz = 4, L = 2048, C = 256, H = 8, D = 32;
static constexpr float SCALE = 0.17677669529663687f;   // 32^-0.5
static constexpr float LOG2E = 1.44269504088896f;
static constexpr float QSCALE = SCALE * LOG2E;         // exp2(S) = softmax exp

__device__ inline float fast_exp2(float x) {
#if __has_builtin(__builtin_amdgcn_exp2f)
    return __builtin_amdgcn_exp2f(x);
#else
    float r; asm("v_exp_f32 %0, %1" : "=v"(r) : "v"(x)); return r;
#endif
}

__device__ inline unsigned cvt_pk_bf16(float lo, float hi) {
    unsigned d;
    asm("v_cvt_pk_bf16_f32 %0, %1, %2" : "=v"(d) : "v"(lo), "v"(hi));
    return d;
}

// ---------------------------------------------------------------------------
// Kernel 1: QKV GEMM with coalesced LDS staging (r17, unchanged).
// ---------------------------------------------------------------------------
__global__ __launch_bounds__(256) void qkv_gemm(
    const float* __restrict__ X, const float* __restrict__ W,
    const float* __restrict__ Bq,
    __bf16* __restrict__ Qw, __bf16* __restrict__ Kw, __bf16* __restrict__ Vt)
{
    constexpr int LDK = 136;
    __shared__ __align__(16) __bf16 smem[128 * LDK + 64 * LDK];
    __bf16* Xs = smem;
    __bf16* Wsh = smem + 128 * LDK;

    const int bm = blockIdx.x & 63, bn = blockIdx.x >> 6;
    const int tid = threadIdx.x, wid = tid >> 6, lane = tid & 63;
    const int lr = lane & 15, lh = lane >> 4;
    const int m0b = bm * 128, n0b = bn * 64;
    const int wm0 = (wid >> 1) * 64, wn0 = (wid & 1) * 32;

    const int srow2 = lane >> 5;
    const int scol  = (lane & 31) * 4;

    f32x4 acc[4][2] = {};

    #pragma unroll
    for (int c = 0; c < 2; ++c) {
        const int k0c = c * 128;
        #pragma unroll
        for (int j = 0; j < 16; ++j) {
            const int row = j * 8 + wid * 2 + srow2;
            const f32x4 v = *(const f32x4*)(X + (size_t)(m0b + row) * 256 + k0c + scol);
            bf16x4 cv; cv[0]=(__bf16)v[0]; cv[1]=(__bf16)v[1]; cv[2]=(__bf16)v[2]; cv[3]=(__bf16)v[3];
            *(bf16x4*)(&Xs[row * LDK + scol]) = cv;
        }
        #pragma unroll
        for (int j = 0; j < 8; ++j) {
            const int row = j * 8 + wid * 2 + srow2;
            const f32x4 v = *(const f32x4*)(W + (size_t)(n0b + row) * 256 + k0c + scol);
            bf16x4 cv; cv[0]=(__bf16)v[0]; cv[1]=(__bf16)v[1]; cv[2]=(__bf16)v[2]; cv[3]=(__bf16)v[3];
            *(bf16x4*)(&Wsh[row * LDK + scol]) = cv;
        }
        __syncthreads();

        #pragma unroll
        for (int ks = 0; ks < 4; ++ks) {
            bf16x8 a[4], b[2];
            #pragma unroll
            for (int mt = 0; mt < 4; ++mt)
                a[mt] = *(const bf16x8*)(&Xs[(wm0 + mt * 16 + lr) * LDK + ks * 32 + lh * 8]);
            #pragma unroll
            for (int nt = 0; nt < 2; ++nt)
                b[nt] = *(const bf16x8*)(&Wsh[(wn0 + nt * 16 + lr) * LDK + ks * 32 + lh * 8]);
            #pragma unroll
            for (int mt = 0; mt < 4; ++mt)
                #pragma unroll
                for (int nt = 0; nt < 2; ++nt)
                    acc[mt][nt] = MFMA16(a[mt], b[nt], acc[mt][nt]);
        }
        __syncthreads();
    }

    const int m0 = m0b + wm0;
    const int n0 = n0b + wn0;
    const int bb  = m0 >> 11;
    const int li0 = m0 & 2047;
    const int h = n0 / 96, r = n0 % 96;
    const int which = r >> 5;
    const int bh = bb * H + h;
    __bf16* sw = smem + wid * 2560;

    if (which == 2) {
        #pragma unroll
        for (int nt = 0; nt < 2; ++nt) {
            const float bias = Bq[n0 + nt * 16 + lr];
            #pragma unroll
            for (int mt = 0; mt < 4; ++mt)
                #pragma unroll
                for (int i = 0; i < 4; ++i)
                    sw[(nt * 16 + lr) * 72 + mt * 16 + lh * 4 + i] =
                        (__bf16)(acc[mt][nt][i] + bias);
        }
        #pragma unroll
        for (int j = 0; j < 4; ++j) {
            const int cch = lane + 64 * j;
            const int d = cch >> 3, lc = (cch & 7) * 8;
            const bf16x8 v = *(const bf16x8*)(&sw[d * 72 + lc]);
            *(bf16x8*)(Vt + ((size_t)bh * D + d) * L + li0 + lc) = v;
        }
    } else {
        const float scl = (which == 0) ? QSCALE : 1.0f;
        #pragma unroll
        for (int nt = 0; nt < 2; ++nt) {
            const float bias = Bq[n0 + nt * 16 + lr];
            #pragma unroll
            for (int mt = 0; mt < 4; ++mt)
                #pragma unroll
                for (int i = 0; i < 4; ++i)
                    sw[(mt * 16 + lh * 4 + i) * 40 + nt * 16 + lr] =
                        (__bf16)((acc[mt][nt][i] + bias) * scl);
        }
        __bf16* dst = (which == 0 ? Qw : Kw) + ((size_t)bh * L + li0) * D;
        #pragma unroll
        for (int j = 0; j < 4; ++j) {
            const int cch = lane + 64 * j;
            const bf16x8 v = *(const bf16x8*)(&sw[(cch >> 2) * 40 + (cch & 3) * 8]);
            *(bf16x8*)(dst + (size_t)cch * 8) = v;
        }
    }
}

// ---------------------------------------------------------------------------
// Kernel 2: flash attention, KV-split 2, 32x32x16 MFMA, in-register P (T12).
// grid 1024 = 32 bh x 32 qt(64 rows); 256 thr (4 waves).
// Wave (qgroup=wid&1, khalf=wid>>1): q-rows qt*64+qgroup*32, keys
// [khalf*1024, +1024). Staging: all 256 thr stage BOTH key-halves' K/V
// tiles (double-buffered). Combine pairs via LDS (aliases staging area).
// ---------------------------------------------------------------------------
__global__ __launch_bounds__(256, 4) void attn_fwd(
    const __bf16* __restrict__ Qw, const __bf16* __restrict__ Kw,
    const __bf16* __restrict__ Vt, __bf16* __restrict__ O)
{
    // 4 panels of (K 64x40 + V 32x72) = 4864 elems; panel (buf,half) at
    // (buf*2+half)*4864. Total 19456 bf16 = 38912 B -> 4 blocks/CU.
    __shared__ __align__(16) __bf16 smem[19456];

    const int bid = blockIdx.x;
    const int bh = ((bid & 7) << 2) | ((bid >> 3) & 3);
    const int qt = bid >> 5;
    const int tid = threadIdx.x, wid = tid >> 6, lane = tid & 63;
    const int lo = lane & 31, hi = lane >> 5;
    const int qgroup = wid & 1, khalf = wid >> 1;
    const int q0 = qt * 64 + qgroup * 32;

    const __bf16* Qb = Qw + (size_t)bh * L * D;
    const __bf16* Kb = Kw + (size_t)bh * L * D;
    const __bf16* Vb = Vt + (size_t)bh * D * L;

    bf16x8 qf[2];
    #pragma unroll
    for (int cl = 0; cl < 2; ++cl)
        qf[cl] = *(const bf16x8*)(Qb + (size_t)(q0 + lo) * D + cl * 16 + hi * 8);

    f32x16 oacc = {};
    float sacc[4] = {0.f, 0.f, 0.f, 0.f};

    // staging coords (each thread: one K row-chunk + one V row-chunk)
    const int krow = tid >> 1, kcol = (tid & 1) * 16;     // K row 0..127
    const int khS = krow >> 6, krl = krow & 63;
    const int vrow = tid >> 2, vcol = (tid & 3) * 16;     // V row 0..63
    const int vhS = vrow >> 5, vd = vrow & 31;

    bf16x8 kA, kB, vA, vB;
#define LOADR(KV) do {                                                         \
    const __bf16* kp = Kb + (size_t)(khS * 1024 + (KV) + krl) * D + kcol;      \
    kA = *(const bf16x8*)kp;  kB = *(const bf16x8*)(kp + 8);                   \
    const __bf16* vp = Vb + (size_t)vd * L + vhS * 1024 + (KV) + vcol;         \
    vA = *(const bf16x8*)vp;  vB = *(const bf16x8*)(vp + 8);                   \
} while (0)
#define WRITEB(BUF) do {                                                       \
    __bf16* kp = smem + ((BUF) * 2 + khS) * 4864 + krl * 40 + kcol;            \
    *(bf16x8*)kp = kA;  *(bf16x8*)(kp + 8) = kB;                               \
    __bf16* vp = smem + ((BUF) * 2 + vhS) * 4864 + 2560 + vd * 72 + vcol;      \
    *(bf16x8*)vp = vA;  *(bf16x8*)(vp + 8) = vB;                               \
} while (0)

    LOADR(0);
    WRITEB(0);

    for (int t = 0; t < 16; ++t) {
        const int cur = t & 1;
        if (t + 1 < 16) LOADR((t + 1) * 64);
        __syncthreads();

        const __bf16* Kp = smem + (cur * 2 + khalf) * 4864;
        const __bf16* Vp = Kp + 2560;

        #pragma unroll
        for (int sub = 0; sub < 2; ++sub) {
            const int kb = sub * 32;

            f32x16 sst = {};
            const bf16x8 ka0 = *(const bf16x8*)(Kp + (kb + lo) * 40 + hi * 8);
            const bf16x8 ka1 = *(const bf16x8*)(Kp + (kb + lo) * 40 + 16 + hi * 8);
            sst = MFMA32(ka0, qf[0], sst);
            sst = MFMA32(ka1, qf[1], sst);

            float p[16];
            #pragma unroll
            for (int r = 0; r < 16; ++r) p[r] = fast_exp2(sst[r]);
            #pragma unroll
            for (int r = 0; r < 16; ++r) sacc[r & 3] += p[r];

            unsigned pk[8];
            #pragma unroll
            for (int j = 0; j < 8; ++j) pk[j] = cvt_pk_bf16(p[2 * j], p[2 * j + 1]);

            unsigned a0 = pk[0], b0 = pk[2];
            unsigned a1 = pk[1], b1 = pk[3];
            unsigned c0 = pk[4], d0 = pk[6];
            unsigned c1 = pk[5], d1 = pk[7];
            asm("v_permlane32_swap_b32 %0, %1" : "+v"(a0), "+v"(b0));
            asm("v_permlane32_swap_b32 %0, %1" : "+v"(a1), "+v"(b1));
            asm("v_permlane32_swap_b32 %0, %1" : "+v"(c0), "+v"(d0));
            asm("v_permlane32_swap_b32 %0, %1" : "+v"(c1), "+v"(d1));
            const u32x4 f0 = {a0, a1, b0, b1};
            const u32x4 f1 = {c0, c1, d0, d1};
            const bf16x8 pf0 = __builtin_bit_cast(bf16x8, f0);
            const bf16x8 pf1 = __builtin_bit_cast(bf16x8, f1);

            const bf16x8 vb0 = *(const bf16x8*)(Vp + lo * 72 + kb + hi * 8);
            const bf16x8 vb1 = *(const bf16x8*)(Vp + lo * 72 + kb + 16 + hi * 8);
            oacc = MFMA32(pf0, vb0, oacc);
            oacc = MFMA32(pf1, vb1, oacc);
        }

        if (t + 1 < 16) WRITEB(cur ^ 1);
    }
#undef LOADR
#undef WRITEB

    float tot = (sacc[0] + sacc[1]) + (sacc[2] + sacc[3]);
    tot += __shfl_xor(tot, 32);

    // cross-half combine: alias combine buffer over staging LDS
    __syncthreads();                      // all staging reads done
    float* cs = (float*)smem;             // [qgroup][lane][20 f32] = 10240 B
    if (khalf == 1) {
        float* p = cs + (qgroup * 64 + lane) * 20;
        #pragma unroll
        for (int r = 0; r < 16; ++r) p[r] = oacc[r];
        p[16] = tot;
    }
    __syncthreads();
    if (khalf == 0) {
        const float* p = cs + (qgroup * 64 + lane) * 20;
        #pragma unroll
        for (int r = 0; r < 16; ++r) oacc[r] += p[r];
        tot += p[16];
        const float inv = 1.f / tot;

        const int b = bh >> 3, h = bh & 7;
        #pragma unroll
        for (int r = 0; r < 16; ++r) {
            const int qr = (r & 3) + 8 * (r >> 2) + 4 * hi;
            const float rs = __shfl(inv, qr);
            O[((size_t)b * L + q0 + qr) * C + h * D + lo] = (__bf16)(oacc[r] * rs);
        }
    }
}

// ---------------------------------------------------------------------------
// Kernel 3: output projection with dense LDS staging. grid 512 = 128 bm x 4 bn,
// 64x64 tile, 256 thr. A(bf16) and W(f32->bf16) staged with dense loads.
// ---------------------------------------------------------------------------
__global__ __launch_bounds__(256) void proj_gemm(
    const __bf16* __restrict__ A, const float* __restrict__ W,
    const float* __restrict__ Bp, float* __restrict__ Out)
{
    constexpr int LDA = 264;                       // 528B rows
    __shared__ __align__(16) __bf16 ps[2 * 64 * LDA];   // A | W, 67584 B
    __bf16* As = ps;
    __bf16* Wsb = ps + 64 * LDA;

    const int bm = blockIdx.x & 127, bn = blockIdx.x >> 7;
    const int tid = threadIdx.x, wid = tid >> 6, lane = tid & 63;
    const int lr = lane & 15, lh = lane >> 4;
    const int m0b = bm * 64, n0b = bn * 64;
    const int wm0 = (wid >> 1) * 32, wn0 = (wid & 1) * 32;

    // stage A: 64 rows x 256 bf16, dense bf16x8 chunks
    #pragma unroll
    for (int j = 0; j < 8; ++j) {
        const int c = tid + 256 * j;
        const int row = c >> 5, col = (c & 31) * 8;
        *(bf16x8*)(&As[row * LDA + col]) =
            *(const bf16x8*)(A + (size_t)(m0b + row) * 256 + col);
    }
    // stage W: 64 rows x 256 f32 -> bf16, dense f32x4 chunks
    #pragma unroll
    for (int j = 0; j < 16; ++j) {
        const int c = tid + 256 * j;
        const int row = c >> 6, col = (c & 63) * 4;
        const f32x4 v = *(const f32x4*)(W + (size_t)(n0b + row) * 256 + col);
        bf16x4 cv; cv[0]=(__bf16)v[0]; cv[1]=(__bf16)v[1]; cv[2]=(__bf16)v[2]; cv[3]=(__bf16)v[3];
        *(bf16x4*)(&Wsb[row * LDA + col]) = cv;
    }
    __syncthreads();

    f32x4 acc[2][2] = {};
    #pragma unroll
    for (int k0 = 0; k0 < 256; k0 += 32) {
        bf16x8 a[2], b[2];
        #pragma unroll
        for (int mt = 0; mt < 2; ++mt)
            a[mt] = *(const bf16x8*)(&As[(wm0 + mt * 16 + lr) * LDA + k0 + lh * 8]);
        #pragma unroll
        for (int nt = 0; nt < 2; ++nt)
            b[nt] = *(const bf16x8*)(&Wsb[(wn0 + nt * 16 + lr) * LDA + k0 + lh * 8]);
        #pragma unroll
        for (int mt = 0; mt < 2; ++mt)
            #pragma unroll
            for (int nt = 0; nt < 2; ++nt)
                acc[mt][nt] = MFMA16(a[mt], b[nt], acc[mt][nt]);
    }

    #pragma unroll
    for (int mt = 0; mt < 2; ++mt) {
        #pragma unroll
        for (int nt = 0; nt < 2; ++nt) {
            const int n = n0b + wn0 + nt * 16 + lr;
            const float bias = Bp[n];
            #pragma unroll
            for (int i = 0; i < 4; ++i) {
                const int m = m0b + wm0 + mt * 16 + lh * 4 + i;
                Out[(size_t)m * 256 + n] = acc[mt][nt][i] + bias;
            }
        }
    }
}

__global__ void fatal_flag(float* Out, int n, float v) {
    int i = blockIdx.x * blockDim.x + threadIdx.x;
    if (i < n) Out[i] = (i == 0) ? v : 0.f;
}

// ---------------------------------------------------------------------------
extern "C" void kernel_launch(void* const* d_in, const int* in_sizes, int n_in,
                              void* d_out, int out_size, void* d_ws, size_t ws_size,
                              hipStream_t stream)
{
    float* out = (float*)d_out;

    const float *x = nullptr, *w_qkv = nullptr, *b_qkv = nullptr,
                *w_proj = nullptr, *b_proj = nullptr;
    for (int i = 0; i < n_in; ++i) {
        switch (in_sizes[i]) {
            case 2097152: x      = (const float*)d_in[i]; break;
            case 196608:  w_qkv  = (const float*)d_in[i]; break;
            case 768:     b_qkv  = (const float*)d_in[i]; break;
            case 65536:   w_proj = (const float*)d_in[i]; break;
            case 256:     b_proj = (const float*)d_in[i]; break;
        }
    }
    if (!x || !w_qkv || !b_qkv || !w_proj || !b_proj) {
        fatal_flag<<<dim3((out_size + 255) / 256), dim3(256), 0, stream>>>(out, out_size, 3e9f);
        return;
    }

    const size_t SEG = (size_t)Bsz * H * L * D;      // 2M elems
    if (ws_size < 4 * SEG * sizeof(__bf16)) {
        fatal_flag<<<dim3((out_size + 255) / 256), dim3(256), 0, stream>>>(out, out_size, 1e9f);
        return;
    }

    __bf16* ws = (__bf16*)d_ws;
    __bf16* Qw = ws;
    __bf16* Kw = ws + SEG;
    __bf16* Vt = ws + 2 * SEG;
    __bf16* Ob = ws + 3 * SEG;

    qkv_gemm<<<dim3(768), dim3(256), 0, stream>>>(x, w_qkv, b_qkv, Qw, Kw, Vt);
    attn_fwd<<<dim3(1024), dim3(256), 0, stream>>>(Qw, Kw, Vt, Ob);
    proj_gemm<<<dim3(512), dim3(256), 0, stream>>>(Ob, w_proj, b_proj, out);
}

// Round 20
// 51.635 us; speedup vs baseline: 1.7626x; 1.1199x over previous
//
#include <hip/hip_runtime.h>
#include <hip/hip_bf16.h>

// Problem: SelfAttention1d  B=4, L=2048, C=256, H=8, D=32.
// dtypes: inputs fp32, output fp32 (r19 = 57.8us; attn ~20, qkv ~17, proj ~5).
// Round 20: qkv software pipeline — chunk-1 global loads ISSUED into regs
// before chunk-0's compute barrier (r17-attn-proven issue-early/write-late
// pattern); both load epochs now hide under compute. attn/proj = r19.

typedef __bf16 bf16x4 __attribute__((ext_vector_type(4)));
typedef __bf16 bf16x8 __attribute__((ext_vector_type(8)));
typedef float  f32x4  __attribute__((ext_vector_type(4)));
typedef float  f32x16 __attribute__((ext_vector_type(16)));
typedef unsigned u32x4 __attribute__((ext_vector_type(4)));

#define MFMA16(a, b, c) __builtin_amdgcn_mfma_f32_16x16x32_bf16((a), (b), (c), 0, 0, 0)
#define MFMA32(a, b, c) __builtin_amdgcn_mfma_f32_32x32x16_bf16((a), (b), (c), 0, 0, 0)

static constexpr int Bsz = 4, L = 2048, C = 256, H = 8, D = 32;
static constexpr float SCALE = 0.17677669529663687f;   // 32^-0.5
static constexpr float LOG2E = 1.44269504088896f;
static constexpr float QSCALE = SCALE * LOG2E;         // exp2(S) = softmax exp

__device__ inline float fast_exp2(float x) {
#if __has_builtin(__builtin_amdgcn_exp2f)
    return __builtin_amdgcn_exp2f(x);
#else
    float r; asm("v_exp_f32 %0, %1" : "=v"(r) : "v"(x)); return r;
#endif
}

__device__ inline unsigned cvt_pk_bf16(float lo, float hi) {
    unsigned d;
    asm("v_cvt_pk_bf16_f32 %0, %1, %2" : "=v"(d) : "v"(lo), "v"(hi));
    return d;
}

// ---------------------------------------------------------------------------
// Kernel 1: QKV GEMM, LDS-staged, software-pipelined across the 2 K-chunks.
// grid 768 = 64 bm x 12 bn, 256 thr (4 waves, wave tile 64x32).
// ---------------------------------------------------------------------------
__global__ __launch_bounds__(256) void qkv_gemm(
    const float* __restrict__ X, const float* __restrict__ W,
    const float* __restrict__ Bq,
    __bf16* __restrict__ Qw, __bf16* __restrict__ Kw, __bf16* __restrict__ Vt)
{
    constexpr int LDK = 136;
    __shared__ __align__(16) __bf16 smem[128 * LDK + 64 * LDK];
    __bf16* Xs = smem;
    __bf16* Wsh = smem + 128 * LDK;

    const int bm = blockIdx.x & 63, bn = blockIdx.x >> 6;
    const int tid = threadIdx.x, wid = tid >> 6, lane = tid & 63;
    const int lr = lane & 15, lh = lane >> 4;
    const int m0b = bm * 128, n0b = bn * 64;
    const int wm0 = (wid >> 1) * 64, wn0 = (wid & 1) * 32;

    const int srow2 = lane >> 5;
    const int scol  = (lane & 31) * 4;

    f32x4 acc[4][2] = {};
    f32x4 xr[16], wr8[8];                   // prefetch registers (one chunk)

#define LOADC(CH) do {                                                        \
    const int k0c = (CH) * 128;                                               \
    _Pragma("unroll")                                                         \
    for (int j = 0; j < 16; ++j) {                                            \
        const int row = j * 8 + wid * 2 + srow2;                              \
        xr[j] = *(const f32x4*)(X + (size_t)(m0b + row) * 256 + k0c + scol);  \
    }                                                                         \
    _Pragma("unroll")                                                         \
    for (int j = 0; j < 8; ++j) {                                             \
        const int row = j * 8 + wid * 2 + srow2;                              \
        wr8[j] = *(const f32x4*)(W + (size_t)(n0b + row) * 256 + k0c + scol); \
    }                                                                         \
} while (0)

#define WRITEC() do {                                                         \
    _Pragma("unroll")                                                         \
    for (int j = 0; j < 16; ++j) {                                            \
        const int row = j * 8 + wid * 2 + srow2;                              \
        bf16x4 cv; cv[0]=(__bf16)xr[j][0]; cv[1]=(__bf16)xr[j][1];            \
                   cv[2]=(__bf16)xr[j][2]; cv[3]=(__bf16)xr[j][3];            \
        *(bf16x4*)(&Xs[row * LDK + scol]) = cv;                               \
    }                                                                         \
    _Pragma("unroll")                                                         \
    for (int j = 0; j < 8; ++j) {                                             \
        const int row = j * 8 + wid * 2 + srow2;                              \
        bf16x4 cv; cv[0]=(__bf16)wr8[j][0]; cv[1]=(__bf16)wr8[j][1];          \
                   cv[2]=(__bf16)wr8[j][2]; cv[3]=(__bf16)wr8[j][3];          \
        *(bf16x4*)(&Wsh[row * LDK + scol]) = cv;                              \
    }                                                                         \
} while (0)

#define COMPUTEC() do {                                                       \
    _Pragma("unroll")                                                         \
    for (int ks = 0; ks < 4; ++ks) {                                          \
        bf16x8 a[4], b[2];                                                    \
        _Pragma("unroll")                                                     \
        for (int mt = 0; mt < 4; ++mt)                                        \
            a[mt] = *(const bf16x8*)(&Xs[(wm0 + mt * 16 + lr) * LDK + ks * 32 + lh * 8]); \
        _Pragma("unroll")                                                     \
        for (int nt = 0; nt < 2; ++nt)                                        \
            b[nt] = *(const bf16x8*)(&Wsh[(wn0 + nt * 16 + lr) * LDK + ks * 32 + lh * 8]); \
        _Pragma("unroll")                                                     \
        for (int mt = 0; mt < 4; ++mt)                                        \
            _Pragma("unroll")                                                 \
            for (int nt = 0; nt < 2; ++nt)                                    \
                acc[mt][nt] = MFMA16(a[mt], b[nt], acc[mt][nt]);              \
    }                                                                         \
} while (0)

    LOADC(0);
    WRITEC();
    LOADC(1);                 // issue chunk-1 loads; in flight during compute0
    __syncthreads();
    COMPUTEC();               // chunk 0
    __syncthreads();
    WRITEC();                 // vmcnt drained during compute0
    __syncthreads();
    COMPUTEC();               // chunk 1
    __syncthreads();          // all LDS reads done before epilogue scratch

#undef LOADC
#undef WRITEC
#undef COMPUTEC

    const int m0 = m0b + wm0;
    const int n0 = n0b + wn0;
    const int bb  = m0 >> 11;
    const int li0 = m0 & 2047;
    const int h = n0 / 96, r = n0 % 96;
    const int which = r >> 5;
    const int bh = bb * H + h;
    __bf16* sw = smem + wid * 2560;

    if (which == 2) {
        #pragma unroll
        for (int nt = 0; nt < 2; ++nt) {
            const float bias = Bq[n0 + nt * 16 + lr];
            #pragma unroll
            for (int mt = 0; mt < 4; ++mt)
                #pragma unroll
                for (int i = 0; i < 4; ++i)
                    sw[(nt * 16 + lr) * 72 + mt * 16 + lh * 4 + i] =
                        (__bf16)(acc[mt][nt][i] + bias);
        }
        #pragma unroll
        for (int j = 0; j < 4; ++j) {
            const int cch = lane + 64 * j;
            const int d = cch >> 3, lc = (cch & 7) * 8;
            const bf16x8 v = *(const bf16x8*)(&sw[d * 72 + lc]);
            *(bf16x8*)(Vt + ((size_t)bh * D + d) * L + li0 + lc) = v;
        }
    } else {
        const float scl = (which == 0) ? QSCALE : 1.0f;
        #pragma unroll
        for (int nt = 0; nt < 2; ++nt) {
            const float bias = Bq[n0 + nt * 16 + lr];
            #pragma unroll
            for (int mt = 0; mt < 4; ++mt)
                #pragma unroll
                for (int i = 0; i < 4; ++i)
                    sw[(mt * 16 + lh * 4 + i) * 40 + nt * 16 + lr] =
                        (__bf16)((acc[mt][nt][i] + bias) * scl);
        }
        __bf16* dst = (which == 0 ? Qw : Kw) + ((size_t)bh * L + li0) * D;
        #pragma unroll
        for (int j = 0; j < 4; ++j) {
            const int cch = lane + 64 * j;
            const bf16x8 v = *(const bf16x8*)(&sw[(cch >> 2) * 40 + (cch & 3) * 8]);
            *(bf16x8*)(dst + (size_t)cch * 8) = v;
        }
    }
}

// ---------------------------------------------------------------------------
// Kernel 2: flash attention, KV-split 2, 32x32x16 MFMA, in-register P (T12).
// (r19, unchanged)
// ---------------------------------------------------------------------------
__global__ __launch_bounds__(256, 4) void attn_fwd(
    const __bf16* __restrict__ Qw, const __bf16* __restrict__ Kw,
    const __bf16* __restrict__ Vt, __bf16* __restrict__ O)
{
    __shared__ __align__(16) __bf16 smem[19456];

    const int bid = blockIdx.x;
    const int bh = ((bid & 7) << 2) | ((bid >> 3) & 3);
    const int qt = bid >> 5;
    const int tid = threadIdx.x, wid = tid >> 6, lane = tid & 63;
    const int lo = lane & 31, hi = lane >> 5;
    const int qgroup = wid & 1, khalf = wid >> 1;
    const int q0 = qt * 64 + qgroup * 32;

    const __bf16* Qb = Qw + (size_t)bh * L * D;
    const __bf16* Kb = Kw + (size_t)bh * L * D;
    const __bf16* Vb = Vt + (size_t)bh * D * L;

    bf16x8 qf[2];
    #pragma unroll
    for (int cl = 0; cl < 2; ++cl)
        qf[cl] = *(const bf16x8*)(Qb + (size_t)(q0 + lo) * D + cl * 16 + hi * 8);

    f32x16 oacc = {};
    float sacc[4] = {0.f, 0.f, 0.f, 0.f};

    const int krow = tid >> 1, kcol = (tid & 1) * 16;
    const int khS = krow >> 6, krl = krow & 63;
    const int vrow = tid >> 2, vcol = (tid & 3) * 16;
    const int vhS = vrow >> 5, vd = vrow & 31;

    bf16x8 kA, kB, vA, vB;
#define LOADR(KV) do {                                                         \
    const __bf16* kp = Kb + (size_t)(khS * 1024 + (KV) + krl) * D + kcol;      \
    kA = *(const bf16x8*)kp;  kB = *(const bf16x8*)(kp + 8);                   \
    const __bf16* vp = Vb + (size_t)vd * L + vhS * 1024 + (KV) + vcol;         \
    vA = *(const bf16x8*)vp;  vB = *(const bf16x8*)(vp + 8);                   \
} while (0)
#define WRITEB(BUF) do {                                                       \
    __bf16* kp = smem + ((BUF) * 2 + khS) * 4864 + krl * 40 + kcol;            \
    *(bf16x8*)kp = kA;  *(bf16x8*)(kp + 8) = kB;                               \
    __bf16* vp = smem + ((BUF) * 2 + vhS) * 4864 + 2560 + vd * 72 + vcol;      \
    *(bf16x8*)vp = vA;  *(bf16x8*)(vp + 8) = vB;                               \
} while (0)

    LOADR(0);
    WRITEB(0);

    for (int t = 0; t < 16; ++t) {
        const int cur = t & 1;
        if (t + 1 < 16) LOADR((t + 1) * 64);
        __syncthreads();

        const __bf16* Kp = smem + (cur * 2 + khalf) * 4864;
        const __bf16* Vp = Kp + 2560;

        #pragma unroll
        for (int sub = 0; sub < 2; ++sub) {
            const int kb = sub * 32;

            f32x16 sst = {};
            const bf16x8 ka0 = *(const bf16x8*)(Kp + (kb + lo) * 40 + hi * 8);
            const bf16x8 ka1 = *(const bf16x8*)(Kp + (kb + lo) * 40 + 16 + hi * 8);
            sst = MFMA32(ka0, qf[0], sst);
            sst = MFMA32(ka1, qf[1], sst);

            float p[16];
            #pragma unroll
            for (int r = 0; r < 16; ++r) p[r] = fast_exp2(sst[r]);
            #pragma unroll
            for (int r = 0; r < 16; ++r) sacc[r & 3] += p[r];

            unsigned pk[8];
            #pragma unroll
            for (int j = 0; j < 8; ++j) pk[j] = cvt_pk_bf16(p[2 * j], p[2 * j + 1]);

            unsigned a0 = pk[0], b0 = pk[2];
            unsigned a1 = pk[1], b1 = pk[3];
            unsigned c0 = pk[4], d0 = pk[6];
            unsigned c1 = pk[5], d1 = pk[7];
            asm("v_permlane32_swap_b32 %0, %1" : "+v"(a0), "+v"(b0));
            asm("v_permlane32_swap_b32 %0, %1" : "+v"(a1), "+v"(b1));
            asm("v_permlane32_swap_b32 %0, %1" : "+v"(c0), "+v"(d0));
            asm("v_permlane32_swap_b32 %0, %1" : "+v"(c1), "+v"(d1));
            const u32x4 f0 = {a0, a1, b0, b1};
            const u32x4 f1 = {c0, c1, d0, d1};
            const bf16x8 pf0 = __builtin_bit_cast(bf16x8, f0);
            const bf16x8 pf1 = __builtin_bit_cast(bf16x8, f1);

            const bf16x8 vb0 = *(const bf16x8*)(Vp + lo * 72 + kb + hi * 8);
            const bf16x8 vb1 = *(const bf16x8*)(Vp + lo * 72 + kb + 16 + hi * 8);
            oacc = MFMA32(pf0, vb0, oacc);
            oacc = MFMA32(pf1, vb1, oacc);
        }

        if (t + 1 < 16) WRITEB(cur ^ 1);
    }
#undef LOADR
#undef WRITEB

    float tot = (sacc[0] + sacc[1]) + (sacc[2] + sacc[3]);
    tot += __shfl_xor(tot, 32);

    __syncthreads();
    float* cs = (float*)smem;
    if (khalf == 1) {
        float* p = cs + (qgroup * 64 + lane) * 20;
        #pragma unroll
        for (int r = 0; r < 16; ++r) p[r] = oacc[r];
        p[16] = tot;
    }
    __syncthreads();
    if (khalf == 0) {
        const float* p = cs + (qgroup * 64 + lane) * 20;
        #pragma unroll
        for (int r = 0; r < 16; ++r) oacc[r] += p[r];
        tot += p[16];
        const float inv = 1.f / tot;

        const int b = bh >> 3, h = bh & 7;
        #pragma unroll
        for (int r = 0; r < 16; ++r) {
            const int qr = (r & 3) + 8 * (r >> 2) + 4 * hi;
            const float rs = __shfl(inv, qr);
            O[((size_t)b * L + q0 + qr) * C + h * D + lo] = (__bf16)(oacc[r] * rs);
        }
    }
}

// ---------------------------------------------------------------------------
// Kernel 3: output projection with dense LDS staging (r19, unchanged).
// ---------------------------------------------------------------------------
__global__ __launch_bounds__(256) void proj_gemm(
    const __bf16* __restrict__ A, const float* __restrict__ W,
    const float* __restrict__ Bp, float* __restrict__ Out)
{
    constexpr int LDA = 264;
    __shared__ __align__(16) __bf16 ps[2 * 64 * LDA];
    __bf16* As = ps;
    __bf16* Wsb = ps + 64 * LDA;

    const int bm = blockIdx.x & 127, bn = blockIdx.x >> 7;
    const int tid = threadIdx.x, wid = tid >> 6, lane = tid & 63;
    const int lr = lane & 15, lh = lane >> 4;
    const int m0b = bm * 64, n0b = bn * 64;
    const int wm0 = (wid >> 1) * 32, wn0 = (wid & 1) * 32;

    #pragma unroll
    for (int j = 0; j < 8; ++j) {
        const int c = tid + 256 * j;
        const int row = c >> 5, col = (c & 31) * 8;
        *(bf16x8*)(&As[row * LDA + col]) =
            *(const bf16x8*)(A + (size_t)(m0b + row) * 256 + col);
    }
    #pragma unroll
    for (int j = 0; j < 16; ++j) {
        const int c = tid + 256 * j;
        const int row = c >> 6, col = (c & 63) * 4;
        const f32x4 v = *(const f32x4*)(W + (size_t)(n0b + row) * 256 + col);
        bf16x4 cv; cv[0]=(__bf16)v[0]; cv[1]=(__bf16)v[1]; cv[2]=(__bf16)v[2]; cv[3]=(__bf16)v[3];
        *(bf16x4*)(&Wsb[row * LDA + col]) = cv;
    }
    __syncthreads();

    f32x4 acc[2][2] = {};
    #pragma unroll
    for (int k0 = 0; k0 < 256; k0 += 32) {
        bf16x8 a[2], b[2];
        #pragma unroll
        for (int mt = 0; mt < 2; ++mt)
            a[mt] = *(const bf16x8*)(&As[(wm0 + mt * 16 + lr) * LDA + k0 + lh * 8]);
        #pragma unroll
        for (int nt = 0; nt < 2; ++nt)
            b[nt] = *(const bf16x8*)(&Wsb[(wn0 + nt * 16 + lr) * LDA + k0 + lh * 8]);
        #pragma unroll
        for (int mt = 0; mt < 2; ++mt)
            #pragma unroll
            for (int nt = 0; nt < 2; ++nt)
                acc[mt][nt] = MFMA16(a[mt], b[nt], acc[mt][nt]);
    }

    #pragma unroll
    for (int mt = 0; mt < 2; ++mt) {
        #pragma unroll
        for (int nt = 0; nt < 2; ++nt) {
            const int n = n0b + wn0 + nt * 16 + lr;
            const float bias = Bp[n];
            #pragma unroll
            for (int i = 0; i < 4; ++i) {
                const int m = m0b + wm0 + mt * 16 + lh * 4 + i;
                Out[(size_t)m * 256 + n] = acc[mt][nt][i] + bias;
            }
        }
    }
}

__global__ void fatal_flag(float* Out, int n, float v) {
    int i = blockIdx.x * blockDim.x + threadIdx.x;
    if (i < n) Out[i] = (i == 0) ? v : 0.f;
}

// ---------------------------------------------------------------------------
extern "C" void kernel_launch(void* const* d_in, const int* in_sizes, int n_in,
                              void* d_out, int out_size, void* d_ws, size_t ws_size,
                              hipStream_t stream)
{
    float* out = (float*)d_out;

    const float *x = nullptr, *w_qkv = nullptr, *b_qkv = nullptr,
                *w_proj = nullptr, *b_proj = nullptr;
    for (int i = 0; i < n_in; ++i) {
        switch (in_sizes[i]) {
            case 2097152: x      = (const float*)d_in[i]; break;
            case 196608:  w_qkv  = (const float*)d_in[i]; break;
            case 768:     b_qkv  = (const float*)d_in[i]; break;
            case 65536:   w_proj = (const float*)d_in[i]; break;
            case 256:     b_proj = (const float*)d_in[i]; break;
        }
    }
    if (!x || !w_qkv || !b_qkv || !w_proj || !b_proj) {
        fatal_flag<<<dim3((out_size + 255) / 256), dim3(256), 0, stream>>>(out, out_size, 3e9f);
        return;
    }

    const size_t SEG = (size_t)Bsz * H * L * D;      // 2M elems
    if (ws_size < 4 * SEG * sizeof(__bf16)) {
        fatal_flag<<<dim3((out_size + 255) / 256), dim3(256), 0, stream>>>(out, out_size, 1e9f);
        return;
    }

    __bf16* ws = (__bf16*)d_ws;
    __bf16* Qw = ws;
    __bf16* Kw = ws + SEG;
    __bf16* Vt = ws + 2 * SEG;
    __bf16* Ob = ws + 3 * SEG;

    qkv_gemm<<<dim3(768), dim3(256), 0, stream>>>(x, w_qkv, b_qkv, Qw, Kw, Vt);
    attn_fwd<<<dim3(1024), dim3(256), 0, stream>>>(Qw, Kw, Vt, Ob);
    proj_gemm<<<dim3(512), dim3(256), 0, stream>>>(Ob, w_proj, b_proj, out);
}